// Round 1
// baseline (302.317 us; speedup 1.0000x reference)
//
#include <hip/hip_runtime.h>

// SigLIP contrastive loss:
//   logits = emb1 @ emb2^T / 0.07           [B,B], B=8192, D=1024
//   loss = ( sum_i softplus(-l_ii) + sum_{i!=j} softplus(l_ij) ) / B
// Fused: bf16 MFMA GEMM with softplus+reduce epilogue (no logits store).

#define B_DIM 8192
#define K_DIM 1024
#define BM 128
#define BK 64

typedef __bf16 bf16x8 __attribute__((ext_vector_type(8)));
typedef float f32x4 __attribute__((ext_vector_type(4)));

__device__ __forceinline__ unsigned short f2bf(float f) {
  // round-to-nearest-even f32 -> bf16
  unsigned int u = __float_as_uint(f);
  u += 0x7FFFu + ((u >> 16) & 1u);
  return (unsigned short)(u >> 16);
}

__global__ void cvt_kernel(const float* __restrict__ in,
                           unsigned short* __restrict__ out, int n4) {
  int i = blockIdx.x * blockDim.x + threadIdx.x;
  int stride = gridDim.x * blockDim.x;
  const float4* in4 = (const float4*)in;
  ushort4* out4 = (ushort4*)out;
  for (; i < n4; i += stride) {
    float4 v = in4[i];
    ushort4 o;
    o.x = f2bf(v.x);
    o.y = f2bf(v.y);
    o.z = f2bf(v.z);
    o.w = f2bf(v.w);
    out4[i] = o;
  }
}

// 128x128 tile, BK=64, 4 waves (2x2), each wave 64x64 = 4x4 MFMA 16x16x32 frags.
// m97 structure: global_load_lds width 16, single LDS buffer, 2 barriers/K-step.
__global__ __launch_bounds__(256) void siglip_gemm(
    const unsigned short* __restrict__ Abf,
    const unsigned short* __restrict__ Bbf,
    float* __restrict__ partials) {
  __shared__ unsigned short As[BM * BK];  // 16 KB, row-major [row][k]
  __shared__ unsigned short Bs[BM * BK];  // 16 KB, row-major [col][k]  (B^T layout)
  __shared__ float wsum[4];

  const int tid = threadIdx.x;
  const int wave = tid >> 6;
  const int lane = tid & 63;
  const int brow = blockIdx.y;
  const int bcol = blockIdx.x;

  const int wr = wave >> 1;  // wave row (0..1) -> 64 rows
  const int wc = wave & 1;   // wave col (0..1) -> 64 cols

  f32x4 acc[4][4];
#pragma unroll
  for (int m = 0; m < 4; ++m)
#pragma unroll
    for (int n = 0; n < 4; ++n)
      acc[m][n] = f32x4{0.f, 0.f, 0.f, 0.f};

  // Staging: per issue t (0..3), 256 threads cover 32 rows x 64 k-elems (4 KB).
  // Wave w writes LDS bytes [t*4096 + w*1024, +1024) = rows t*32+w*8 .. +8,
  // matching lane order (lane l -> row t*32+w*8+l/8, 16B chunk l%8).
  const int srow = tid >> 3;          // 0..31
  const int schunk = (tid & 7) * 8;   // element offset within BK
  const unsigned short* Ag = Abf + (size_t)(brow * BM + srow) * K_DIM + schunk;
  const unsigned short* Bg = Bbf + (size_t)(bcol * BM + srow) * K_DIM + schunk;

  const int lr = lane & 15;        // fragment row (A) / col (B)
  const int lk = (lane >> 4) * 8;  // k offset within 32-slice

  for (int kt = 0; kt < K_DIM / BK; ++kt) {
    const int k0 = kt * BK;
    __syncthreads();  // previous compute done before overwrite
#pragma unroll
    for (int t = 0; t < 4; ++t) {
      __builtin_amdgcn_global_load_lds(
          (const __attribute__((address_space(1))) void*)(const void*)(Ag + (size_t)t * 32 * K_DIM + k0),
          (__attribute__((address_space(3))) void*)(void*)((char*)As + t * 4096 + wave * 1024),
          16, 0, 0);
    }
#pragma unroll
    for (int t = 0; t < 4; ++t) {
      __builtin_amdgcn_global_load_lds(
          (const __attribute__((address_space(1))) void*)(const void*)(Bg + (size_t)t * 32 * K_DIM + k0),
          (__attribute__((address_space(3))) void*)(void*)((char*)Bs + t * 4096 + wave * 1024),
          16, 0, 0);
    }
    __syncthreads();  // drains vmcnt: staged tile visible

#pragma unroll
    for (int ks = 0; ks < 2; ++ks) {
      bf16x8 a[4], b[4];
#pragma unroll
      for (int m = 0; m < 4; ++m)
        a[m] = *reinterpret_cast<const bf16x8*>(
            &As[(wr * 64 + m * 16 + lr) * BK + ks * 32 + lk]);
#pragma unroll
      for (int n = 0; n < 4; ++n)
        b[n] = *reinterpret_cast<const bf16x8*>(
            &Bs[(wc * 64 + n * 16 + lr) * BK + ks * 32 + lk]);
#pragma unroll
      for (int m = 0; m < 4; ++m)
#pragma unroll
        for (int n = 0; n < 4; ++n)
          acc[m][n] = __builtin_amdgcn_mfma_f32_16x16x32_bf16(a[m], b[n],
                                                              acc[m][n], 0, 0, 0);
    }
  }

  // Epilogue: softplus + reduce. C/D layout: col = lane&15, row = (lane>>4)*4 + r.
  const float INV_T = 1.0f / 0.07f;
  float lsum = 0.f;
  const int rbase = brow * BM + wr * 64 + (lane >> 4) * 4;
  const int cbase = bcol * BM + wc * 64 + (lane & 15);
#pragma unroll
  for (int m = 0; m < 4; ++m) {
#pragma unroll
    for (int n = 0; n < 4; ++n) {
#pragma unroll
      for (int r = 0; r < 4; ++r) {
        int row = rbase + m * 16 + r;
        int col = cbase + n * 16;
        float x = acc[m][n][r] * INV_T;
        if (row == col) x = -x;  // diagonal: softplus(-l_ii)
        // softplus(x) = max(x,0) + log1p(exp(-|x|))
        lsum += fmaxf(x, 0.f) + log1pf(__expf(-fabsf(x)));
      }
    }
  }
#pragma unroll
  for (int off = 32; off > 0; off >>= 1) lsum += __shfl_down(lsum, off);
  if (lane == 0) wsum[wave] = lsum;
  __syncthreads();
  if (tid == 0)
    partials[blockIdx.y * gridDim.x + blockIdx.x] =
        wsum[0] + wsum[1] + wsum[2] + wsum[3];
}

__global__ void reduce_kernel(const float* __restrict__ partials, int n,
                              float* __restrict__ out) {
  __shared__ float s[256];
  float v = 0.f;
  for (int i = threadIdx.x; i < n; i += 256) v += partials[i];
  s[threadIdx.x] = v;
  __syncthreads();
  for (int off = 128; off > 0; off >>= 1) {
    if ((int)threadIdx.x < off) s[threadIdx.x] += s[threadIdx.x + off];
    __syncthreads();
  }
  if (threadIdx.x == 0) out[0] = s[0] / (float)B_DIM;
}

extern "C" void kernel_launch(void* const* d_in, const int* in_sizes, int n_in,
                              void* d_out, int out_size, void* d_ws, size_t ws_size,
                              hipStream_t stream) {
  const float* emb1 = (const float*)d_in[0];
  const float* emb2 = (const float*)d_in[1];

  unsigned short* Abf = (unsigned short*)d_ws;                      // 16 MB
  unsigned short* Bbf = Abf + (size_t)B_DIM * K_DIM;                // 16 MB
  float* partials = (float*)(Bbf + (size_t)B_DIM * K_DIM);          // 16 KB

  const int n4 = B_DIM * K_DIM / 4;
  cvt_kernel<<<2048, 256, 0, stream>>>(emb1, Abf, n4);
  cvt_kernel<<<2048, 256, 0, stream>>>(emb2, Bbf, n4);

  dim3 grid(B_DIM / BM, B_DIM / BM);
  siglip_gemm<<<grid, 256, 0, stream>>>(Abf, Bbf, partials);

  const int nparts = (B_DIM / BM) * (B_DIM / BM);
  reduce_kernel<<<1, 256, 0, stream>>>(partials, nparts, (float*)d_out);
}

// Round 2
// 231.109 us; speedup vs baseline: 1.3081x; 1.3081x over previous
//
#include <hip/hip_runtime.h>

// SigLIP contrastive loss:
//   logits = emb1 @ emb2^T / 0.07           [B,B], B=8192, D=1024
//   loss = ( sum_i softplus(-l_ii) + sum_{i!=j} softplus(l_ij) ) / B
// Fused: bf16 MFMA GEMM with softplus+reduce epilogue (no logits store).
// R1: cheap softplus (v_exp/v_log), 1/T folded into A cvt, diag check hoisted.

#define B_DIM 8192
#define K_DIM 1024
#define BM 128
#define BK 64

typedef __bf16 bf16x8 __attribute__((ext_vector_type(8)));
typedef float f32x4 __attribute__((ext_vector_type(4)));

__device__ __forceinline__ unsigned short f2bf(float f) {
  // round-to-nearest-even f32 -> bf16
  unsigned int u = __float_as_uint(f);
  u += 0x7FFFu + ((u >> 16) & 1u);
  return (unsigned short)(u >> 16);
}

__global__ void cvt_kernel(const float* __restrict__ in,
                           unsigned short* __restrict__ out, int n4,
                           float scale) {
  int i = blockIdx.x * blockDim.x + threadIdx.x;
  int stride = gridDim.x * blockDim.x;
  const float4* in4 = (const float4*)in;
  ushort4* out4 = (ushort4*)out;
  for (; i < n4; i += stride) {
    float4 v = in4[i];
    ushort4 o;
    o.x = f2bf(v.x * scale);
    o.y = f2bf(v.y * scale);
    o.z = f2bf(v.z * scale);
    o.w = f2bf(v.w * scale);
    out4[i] = o;
  }
}

// Cheap softplus accumulate: softplus(x) = max(x,0) + log(1+exp(-|x|)).
// Correction term sums to ~12 in the final loss (threshold 2.98e4) so the
// fast v_exp/v_log path is far more accurate than needed.
template <bool DIAG>
__device__ __forceinline__ float softplus_sum(const f32x4 acc[4][4], int rbase,
                                              int cbase) {
  float lin = 0.f, cor = 0.f;
#pragma unroll
  for (int m = 0; m < 4; ++m) {
#pragma unroll
    for (int n = 0; n < 4; ++n) {
#pragma unroll
      for (int r = 0; r < 4; ++r) {
        float x = acc[m][n][r];
        if (DIAG) {
          int row = rbase + m * 16 + r;
          int col = cbase + n * 16;
          if (row == col) x = -x;  // diagonal: softplus(-l_ii)
        }
        lin += fmaxf(x, 0.f);
        cor += __logf(1.f + __expf(-fabsf(x)));
      }
    }
  }
  return lin + cor;
}

// 128x128 tile, BK=64, 4 waves (2x2), each wave 64x64 = 4x4 MFMA 16x16x32 frags.
// m97 structure: global_load_lds width 16, single LDS buffer, 2 barriers/K-step.
__global__ __launch_bounds__(256) void siglip_gemm(
    const unsigned short* __restrict__ Abf,
    const unsigned short* __restrict__ Bbf,
    float* __restrict__ partials) {
  __shared__ unsigned short As[BM * BK];  // 16 KB, row-major [row][k]
  __shared__ unsigned short Bs[BM * BK];  // 16 KB, row-major [col][k]  (B^T layout)
  __shared__ float wsum[4];

  const int tid = threadIdx.x;
  const int wave = tid >> 6;
  const int lane = tid & 63;
  const int brow = blockIdx.y;
  const int bcol = blockIdx.x;

  const int wr = wave >> 1;  // wave row (0..1) -> 64 rows
  const int wc = wave & 1;   // wave col (0..1) -> 64 cols

  f32x4 acc[4][4];
#pragma unroll
  for (int m = 0; m < 4; ++m)
#pragma unroll
    for (int n = 0; n < 4; ++n)
      acc[m][n] = f32x4{0.f, 0.f, 0.f, 0.f};

  // Staging: per issue t (0..3), 256 threads cover 32 rows x 64 k-elems (4 KB).
  const int srow = tid >> 3;          // 0..31
  const int schunk = (tid & 7) * 8;   // element offset within BK
  const unsigned short* Ag = Abf + (size_t)(brow * BM + srow) * K_DIM + schunk;
  const unsigned short* Bg = Bbf + (size_t)(bcol * BM + srow) * K_DIM + schunk;

  const int lr = lane & 15;        // fragment row (A) / col (B)
  const int lk = (lane >> 4) * 8;  // k offset within 32-slice

  for (int kt = 0; kt < K_DIM / BK; ++kt) {
    const int k0 = kt * BK;
    __syncthreads();  // previous compute done before overwrite
#pragma unroll
    for (int t = 0; t < 4; ++t) {
      __builtin_amdgcn_global_load_lds(
          (const __attribute__((address_space(1))) void*)(const void*)(Ag + (size_t)t * 32 * K_DIM + k0),
          (__attribute__((address_space(3))) void*)(void*)((char*)As + t * 4096 + wave * 1024),
          16, 0, 0);
    }
#pragma unroll
    for (int t = 0; t < 4; ++t) {
      __builtin_amdgcn_global_load_lds(
          (const __attribute__((address_space(1))) void*)(const void*)(Bg + (size_t)t * 32 * K_DIM + k0),
          (__attribute__((address_space(3))) void*)(void*)((char*)Bs + t * 4096 + wave * 1024),
          16, 0, 0);
    }
    __syncthreads();  // drains vmcnt: staged tile visible

#pragma unroll
    for (int ks = 0; ks < 2; ++ks) {
      bf16x8 a[4], b[4];
#pragma unroll
      for (int m = 0; m < 4; ++m)
        a[m] = *reinterpret_cast<const bf16x8*>(
            &As[(wr * 64 + m * 16 + lr) * BK + ks * 32 + lk]);
#pragma unroll
      for (int n = 0; n < 4; ++n)
        b[n] = *reinterpret_cast<const bf16x8*>(
            &Bs[(wc * 64 + n * 16 + lr) * BK + ks * 32 + lk]);
#pragma unroll
      for (int m = 0; m < 4; ++m)
#pragma unroll
        for (int n = 0; n < 4; ++n)
          acc[m][n] = __builtin_amdgcn_mfma_f32_16x16x32_bf16(a[m], b[n],
                                                              acc[m][n], 0, 0, 0);
    }
  }

  // Epilogue: softplus + reduce. C/D layout: col = lane&15, row = (lane>>4)*4 + r.
  const int rbase = brow * BM + wr * 64 + (lane >> 4) * 4;
  const int cbase = bcol * BM + wc * 64 + (lane & 15);
  float lsum;
  if (brow == bcol)
    lsum = softplus_sum<true>(acc, rbase, cbase);
  else
    lsum = softplus_sum<false>(acc, rbase, cbase);

#pragma unroll
  for (int off = 32; off > 0; off >>= 1) lsum += __shfl_down(lsum, off);
  if (lane == 0) wsum[wave] = lsum;
  __syncthreads();
  if (tid == 0)
    partials[blockIdx.y * gridDim.x + blockIdx.x] =
        wsum[0] + wsum[1] + wsum[2] + wsum[3];
}

__global__ void reduce_kernel(const float* __restrict__ partials, int n,
                              float* __restrict__ out) {
  __shared__ float s[256];
  float v = 0.f;
  for (int i = threadIdx.x; i < n; i += 256) v += partials[i];
  s[threadIdx.x] = v;
  __syncthreads();
  for (int off = 128; off > 0; off >>= 1) {
    if ((int)threadIdx.x < off) s[threadIdx.x] += s[threadIdx.x + off];
    __syncthreads();
  }
  if (threadIdx.x == 0) out[0] = s[0] / (float)B_DIM;
}

extern "C" void kernel_launch(void* const* d_in, const int* in_sizes, int n_in,
                              void* d_out, int out_size, void* d_ws, size_t ws_size,
                              hipStream_t stream) {
  const float* emb1 = (const float*)d_in[0];
  const float* emb2 = (const float*)d_in[1];

  unsigned short* Abf = (unsigned short*)d_ws;                      // 16 MB
  unsigned short* Bbf = Abf + (size_t)B_DIM * K_DIM;                // 16 MB
  float* partials = (float*)(Bbf + (size_t)B_DIM * K_DIM);          // 16 KB

  const int n4 = B_DIM * K_DIM / 4;
  const float INV_T = 1.0f / 0.07f;
  cvt_kernel<<<2048, 256, 0, stream>>>(emb1, Abf, n4, INV_T);  // fold 1/T into A
  cvt_kernel<<<2048, 256, 0, stream>>>(emb2, Bbf, n4, 1.0f);

  dim3 grid(B_DIM / BM, B_DIM / BM);
  siglip_gemm<<<grid, 256, 0, stream>>>(Abf, Bbf, partials);

  const int nparts = (B_DIM / BM) * (B_DIM / BM);
  reduce_kernel<<<1, 256, 0, stream>>>(partials, nparts, (float*)d_out);
}

// Round 3
// 144.029 us; speedup vs baseline: 2.0990x; 1.6046x over previous
//
#include <hip/hip_runtime.h>

// SigLIP contrastive loss:
//   logits = emb1 @ emb2^T / 0.07           [B,B], B=8192, D=1024
//   loss = ( sum_i softplus(-l_ii) + sum_{i!=j} softplus(l_ij) ) / B
// R2: MX-fp8 (e4m3, unit E8M0 scales) mfma_scale_f32_16x16x128_f8f6f4 on the
// same m97 128x128 structure (m148: 1628 TF). Fast softplus epilogue kept.

#define B_DIM 8192
#define K_DIM 1024
#define BM 128
#define BK 128  // fp8 elements (= bytes) per K-step

typedef int i32x8 __attribute__((ext_vector_type(8)));
typedef float f32x4 __attribute__((ext_vector_type(4)));

// f32 -> OCP e4m3 (hardware cvt, saturating), 8 elems/thread/iter.
__global__ void cvt_fp8_kernel(const float* __restrict__ in,
                               unsigned int* __restrict__ out, int n8,
                               float scale) {
  int i = blockIdx.x * blockDim.x + threadIdx.x;
  int stride = gridDim.x * blockDim.x;
  const float4* in4 = (const float4*)in;
  uint2* out2 = (uint2*)out;
  for (; i < n8; i += stride) {
    float4 v0 = in4[2 * i];
    float4 v1 = in4[2 * i + 1];
    unsigned int w0 = 0, w1 = 0;
    w0 = __builtin_amdgcn_cvt_pk_fp8_f32(v0.x * scale, v0.y * scale, w0, 0);
    w0 = __builtin_amdgcn_cvt_pk_fp8_f32(v0.z * scale, v0.w * scale, w0, 1);
    w1 = __builtin_amdgcn_cvt_pk_fp8_f32(v1.x * scale, v1.y * scale, w1, 0);
    w1 = __builtin_amdgcn_cvt_pk_fp8_f32(v1.z * scale, v1.w * scale, w1, 1);
    out2[i] = make_uint2(w0, w1);
  }
}

// Cheap softplus accumulate: softplus(x) = max(x,0) + log(1+exp(-|x|)).
template <bool DIAG>
__device__ __forceinline__ float softplus_sum(const f32x4 acc[4][4], int rbase,
                                              int cbase) {
  float lin = 0.f, cor = 0.f;
#pragma unroll
  for (int m = 0; m < 4; ++m) {
#pragma unroll
    for (int n = 0; n < 4; ++n) {
#pragma unroll
      for (int r = 0; r < 4; ++r) {
        float x = acc[m][n][r];
        if (DIAG) {
          int row = rbase + m * 16 + r;
          int col = cbase + n * 16;
          if (row == col) x = -x;  // diagonal: softplus(-l_ii)
        }
        lin += fmaxf(x, 0.f);
        cor += __logf(1.f + __expf(-fabsf(x)));
      }
    }
  }
  return lin + cor;
}

// 128x128 tile, BK=128 fp8, 4 waves (2x2), each wave 64x64 = 4x4 frags of
// 16x16. One mfma_scale_f32_16x16x128_f8f6f4 per frag per K-step (8 K-steps).
// A/B frag layout: lane&15 = row/col, k = (lane>>4)*32 + byte(0..31); each
// lane's 32 k-elems = one MX scale block; scale byte 0x7F = 2^0 = 1.0.
__global__ __launch_bounds__(256) void siglip_gemm(
    const unsigned char* __restrict__ A8,
    const unsigned char* __restrict__ B8,
    float* __restrict__ partials) {
  __shared__ unsigned char As[BM * BK];  // 16 KB  [row][k] bytes
  __shared__ unsigned char Bs[BM * BK];  // 16 KB  [col][k] bytes
  __shared__ float wsum[4];

  const int tid = threadIdx.x;
  const int wave = tid >> 6;
  const int lane = tid & 63;
  const int brow = blockIdx.y;
  const int bcol = blockIdx.x;

  const int wr = wave >> 1;  // wave row (0..1) -> 64 rows
  const int wc = wave & 1;   // wave col (0..1) -> 64 cols

  f32x4 acc[4][4];
#pragma unroll
  for (int m = 0; m < 4; ++m)
#pragma unroll
    for (int n = 0; n < 4; ++n)
      acc[m][n] = f32x4{0.f, 0.f, 0.f, 0.f};

  // Staging: per issue t (0..3), 256 threads cover 32 rows x 128 bytes (4 KB).
  // lane order matches linear LDS: tid -> row tid/8, 16B chunk tid%8.
  const int srow = tid >> 3;               // 0..31
  const int schunk = (tid & 7) * 16;       // byte offset within BK
  const unsigned char* Ag = A8 + (size_t)(brow * BM + srow) * K_DIM + schunk;
  const unsigned char* Bg = B8 + (size_t)(bcol * BM + srow) * K_DIM + schunk;

  const int lr = lane & 15;          // frag row (A) / col (B)
  const int lkb = (lane >> 4) * 32;  // k byte offset

  for (int kt = 0; kt < K_DIM / BK; ++kt) {
    const int k0 = kt * BK;  // byte offset in row
    __syncthreads();         // previous compute done before overwrite
#pragma unroll
    for (int t = 0; t < 4; ++t) {
      __builtin_amdgcn_global_load_lds(
          (const __attribute__((address_space(1))) void*)(const void*)(Ag + (size_t)t * 32 * K_DIM + k0),
          (__attribute__((address_space(3))) void*)(void*)(As + t * 4096 + wave * 1024),
          16, 0, 0);
    }
#pragma unroll
    for (int t = 0; t < 4; ++t) {
      __builtin_amdgcn_global_load_lds(
          (const __attribute__((address_space(1))) void*)(const void*)(Bg + (size_t)t * 32 * K_DIM + k0),
          (__attribute__((address_space(3))) void*)(void*)(Bs + t * 4096 + wave * 1024),
          16, 0, 0);
    }
    __syncthreads();  // drains vmcnt: staged tile visible

    i32x8 bfrag[4];
#pragma unroll
    for (int n = 0; n < 4; ++n)
      bfrag[n] = *reinterpret_cast<const i32x8*>(
          &Bs[(wc * 64 + n * 16 + lr) * BK + lkb]);
#pragma unroll
    for (int m = 0; m < 4; ++m) {
      i32x8 afrag = *reinterpret_cast<const i32x8*>(
          &As[(wr * 64 + m * 16 + lr) * BK + lkb]);
#pragma unroll
      for (int n = 0; n < 4; ++n)
        acc[m][n] = __builtin_amdgcn_mfma_scale_f32_16x16x128_f8f6f4(
            afrag, bfrag[n], acc[m][n], 0, 0, /*sel_a=*/0, /*scale_a=*/127,
            /*sel_b=*/0, /*scale_b=*/127);
    }
  }

  // Epilogue: softplus + reduce. C/D 16x16 map: col=lane&15, row=(lane>>4)*4+r.
  const int rbase = brow * BM + wr * 64 + (lane >> 4) * 4;
  const int cbase = bcol * BM + wc * 64 + (lane & 15);
  float lsum;
  if (brow == bcol)
    lsum = softplus_sum<true>(acc, rbase, cbase);
  else
    lsum = softplus_sum<false>(acc, rbase, cbase);

#pragma unroll
  for (int off = 32; off > 0; off >>= 1) lsum += __shfl_down(lsum, off);
  if (lane == 0) wsum[wave] = lsum;
  __syncthreads();
  if (tid == 0)
    partials[blockIdx.y * gridDim.x + blockIdx.x] =
        wsum[0] + wsum[1] + wsum[2] + wsum[3];
}

__global__ void reduce_kernel(const float* __restrict__ partials, int n,
                              float* __restrict__ out) {
  __shared__ float s[256];
  float v = 0.f;
  for (int i = threadIdx.x; i < n; i += 256) v += partials[i];
  s[threadIdx.x] = v;
  __syncthreads();
  for (int off = 128; off > 0; off >>= 1) {
    if ((int)threadIdx.x < off) s[threadIdx.x] += s[threadIdx.x + off];
    __syncthreads();
  }
  if (threadIdx.x == 0) out[0] = s[0] / (float)B_DIM;
}

extern "C" void kernel_launch(void* const* d_in, const int* in_sizes, int n_in,
                              void* d_out, int out_size, void* d_ws, size_t ws_size,
                              hipStream_t stream) {
  const float* emb1 = (const float*)d_in[0];
  const float* emb2 = (const float*)d_in[1];

  unsigned char* A8 = (unsigned char*)d_ws;                    // 8 MB
  unsigned char* B8 = A8 + (size_t)B_DIM * K_DIM;              // 8 MB
  float* partials = (float*)(B8 + (size_t)B_DIM * K_DIM);      // 16 KB

  const int n8 = B_DIM * K_DIM / 8;
  const float INV_T = 1.0f / 0.07f;
  cvt_fp8_kernel<<<1024, 256, 0, stream>>>(emb1, (unsigned int*)A8, n8, INV_T);
  cvt_fp8_kernel<<<1024, 256, 0, stream>>>(emb2, (unsigned int*)B8, n8, 1.0f);

  dim3 grid(B_DIM / BM, B_DIM / BM);
  siglip_gemm<<<grid, 256, 0, stream>>>(A8, B8, partials);

  const int nparts = (B_DIM / BM) * (B_DIM / BM);
  reduce_kernel<<<1, 256, 0, stream>>>(partials, nparts, (float*)d_out);
}